// Round 2
// baseline (113.371 us; speedup 1.0000x reference)
//
#include <hip/hip_runtime.h>

// FeatureWithRelativePosition: fused pairwise-dist -> Linear(4096->64) -> LN -> SiLU
// BS=4, N=4096, FEAT=64. fp32 in/out, bf16 MFMA inner product, fp32 accumulate.
//
// R5b: wave-private K-split, ZERO in-loop barriers (hardened resubmit of R5).
//     8 waves/block; each wave owns a 32-k slice per 256-k chunk and computes
//     the full 64x64 tile for it (4 A-frags x 4 B-frags = 16 MFMAs/kstep).
//     W staged per-wave (4 KiB slices) via global_load_lds, double-buffered,
//     synced with a wave-local counted s_waitcnt vmcnt(4) -- never drained to
//     0 inside the loop. Hardening vs R5: explicit vmcnt(0) drains before the
//     prologue barrier (chunk-0 DMA) and before the K-merge barrier (wrap
//     dummy DMA must not land into the reused merge scratch) instead of
//     relying on compiler-emitted barrier drains.

typedef float f32x4 __attribute__((ext_vector_type(4)));
typedef __bf16 bf16x8 __attribute__((ext_vector_type(8)));

union BF8 { bf16x8 v; uint4 u; };

#define N_PTS 4096
#define FEATD 64
#define BK 256
#define NCH (N_PTS / BK)

// ---- pre-pass: W fp32 [64][4096] -> bf16 granule-major Wbt[512][64][8] ----
// uint4 slot (G*64 + f) holds W[f][G*8 .. G*8+7] as bf16.
__global__ void wconv_kernel(const float* __restrict__ W,
                             unsigned short* __restrict__ Wbt) {
  int gid = blockIdx.x * blockDim.x + threadIdx.x;  // 32768 = 64 f * 512 G
  int f = gid >> 9, m8 = gid & 511;
  const float4* src = (const float4*)(W + (size_t)f * N_PTS + m8 * 8);
  float4 a = src[0], b = src[1];
  BF8 o;
  o.v[0] = (__bf16)a.x; o.v[1] = (__bf16)a.y; o.v[2] = (__bf16)a.z; o.v[3] = (__bf16)a.w;
  o.v[4] = (__bf16)b.x; o.v[5] = (__bf16)b.y; o.v[6] = (__bf16)b.z; o.v[7] = (__bf16)b.w;
  ((uint4*)Wbt)[(size_t)m8 * 64 + f] = o.u;
}

__device__ __forceinline__ void load_lds16(const void* g, void* l) {
  __builtin_amdgcn_global_load_lds(
      (const __attribute__((address_space(1))) void*)g,
      (__attribute__((address_space(3))) void*)l, 16, 0, 0);
}

// grid = 256 blocks (batch = bid>>6, rowtile = (bid&63)*64), block = 512 thr.
// wave (0..7) = K-slice: per chunk it owns granules wave*4..wave*4+3 (32 k).
__global__ __launch_bounds__(512, 2) void frp_kernel(
    const float* __restrict__ pos, const float* __restrict__ W,
    const float* __restrict__ bias, const float* __restrict__ gamma,
    const float* __restrict__ beta, const unsigned short* __restrict__ Wbt,
    float* __restrict__ out) {
  __shared__ uint4 Wall[2][8][256];          // 64 KiB: [buf][wave][g*64+f-slot]
  __shared__ __align__(16) float Px[N_PTS];  // 16 KiB each, SoA
  __shared__ __align__(16) float Py[N_PTS];
  __shared__ __align__(16) float Pz[N_PTS];

  const int tid = threadIdx.x;
  const int lane = tid & 63;
  const int wave = tid >> 6;       // 0..7: K-slice
  const int fx = lane & 15;
  const int q = lane >> 4;         // k-granule within the wave's 32-k slice

  const int batch = blockIdx.x >> 6;
  const int nb = (blockIdx.x & 63) * 64;
  const float* posB = pos + (size_t)batch * N_PTS * 3;

  // ---- stage ALL positions SoA (once). 512 thr x 8 pts, float4 in/out. ----
  {
    const float4* p4 = (const float4*)posB;
    float4 f0 = p4[tid * 6 + 0], f1 = p4[tid * 6 + 1], f2 = p4[tid * 6 + 2];
    float4 f3 = p4[tid * 6 + 3], f4 = p4[tid * 6 + 4], f5 = p4[tid * 6 + 5];
    ((float4*)Px)[tid * 2 + 0] = make_float4(f0.x, f0.w, f1.z, f2.y);
    ((float4*)Px)[tid * 2 + 1] = make_float4(f3.x, f3.w, f4.z, f5.y);
    ((float4*)Py)[tid * 2 + 0] = make_float4(f0.y, f1.x, f1.w, f2.z);
    ((float4*)Py)[tid * 2 + 1] = make_float4(f3.y, f4.x, f4.w, f5.z);
    ((float4*)Pz)[tid * 2 + 0] = make_float4(f0.z, f1.y, f2.x, f2.w);
    ((float4*)Pz)[tid * 2 + 1] = make_float4(f3.z, f4.y, f5.x, f5.w);
  }

  const bool useWb = (Wbt != nullptr);

  if (useWb) {
    // DMA chunk 0's own slice.
#pragma unroll
    for (int i = 0; i < 4; ++i)
      load_lds16(Wbt + ((size_t)((wave * 4 + i) * 64 + lane)) * 8,
                 &Wall[0][wave][i * 64 + lane]);
  }

  f32x4 acc[4][4];
#pragma unroll
  for (int a = 0; a < 4; ++a)
#pragma unroll
    for (int t = 0; t < 4; ++t) acc[a][t] = (f32x4){0.f, 0.f, 0.f, 0.f};

  // explicit drain: chunk-0 DMA MUST have landed before any wave reads it.
  if (useWb) asm volatile("s_waitcnt vmcnt(0)" ::: "memory");
  __syncthreads();  // positions staged + chunk-0 landed. LAST barrier until merge.

  // this lane's four A-rows (A-frag row = lane&15), broadcast reads from LDS
  float pxr[4], pyr[4], pzr[4];
#pragma unroll
  for (int a = 0; a < 4; ++a) {
    int r = nb + a * 16 + fx;
    pxr[a] = Px[r]; pyr[a] = Py[r]; pzr[a] = Pz[r];
  }

  const f32x4* Px4 = (const f32x4*)Px;
  const f32x4* Py4 = (const f32x4*)Py;
  const f32x4* Pz4 = (const f32x4*)Pz;

#pragma unroll 2
  for (int c = 0; c < NCH; ++c) {
    if (useWb) {
      // DMA next chunk's slice (wrap to 0 on last iter; dummy, never read --
      // but required so the in-loop vmcnt(4) still covers chunk 15's loads).
      const int cn = (c + 1) & (NCH - 1);
      const int bufn = (c + 1) & 1;
#pragma unroll
      for (int i = 0; i < 4; ++i)
        load_lds16(Wbt + ((size_t)((cn * 32 + wave * 4 + i) * 64 + lane)) * 8,
                   &Wall[bufn][wave][i * 64 + lane]);
    } else {
      // fallback: inline fp32->bf16 conversion of own slice (single-buffered)
#pragma unroll
      for (int i = 0; i < 4; ++i) {
        const float4* src =
            (const float4*)(W + (size_t)lane * N_PTS + c * BK + (wave * 4 + i) * 8);
        float4 a4 = src[0], b4 = src[1];
        BF8 o;
        o.v[0] = (__bf16)a4.x; o.v[1] = (__bf16)a4.y; o.v[2] = (__bf16)a4.z; o.v[3] = (__bf16)a4.w;
        o.v[4] = (__bf16)b4.x; o.v[5] = (__bf16)b4.y; o.v[6] = (__bf16)b4.z; o.v[7] = (__bf16)b4.w;
        Wall[0][wave][i * 64 + lane] = o.u;
      }
    }

    // positions for this wave's 4 granules (16-way broadcast, reused x4 rows)
    const int m4 = c * 64 + (wave * 4 + q) * 2;
    f32x4 xa = Px4[m4], xb = Px4[m4 + 1];
    f32x4 ya = Py4[m4], yb = Py4[m4 + 1];
    f32x4 za = Pz4[m4], zb = Pz4[m4 + 1];

    bf16x8 af[4];
#pragma unroll
    for (int a = 0; a < 4; ++a) {
      f32x4 dx = xa - pxr[a], dy = ya - pyr[a], dz = za - pzr[a];
      f32x4 sq = dx * dx + dy * dy + dz * dz;
#pragma unroll
      for (int j = 0; j < 4; ++j) af[a][j] = (__bf16)__builtin_amdgcn_sqrtf(sq[j]);
      dx = xb - pxr[a]; dy = yb - pyr[a]; dz = zb - pzr[a];
      sq = dx * dx + dy * dy + dz * dz;
#pragma unroll
      for (int j = 0; j < 4; ++j) af[a][4 + j] = (__bf16)__builtin_amdgcn_sqrtf(sq[j]);
    }

    if (useWb) {
      // wave-local sync: the 4 outstanding = just-issued next-chunk DMAs;
      // waiting to 4 guarantees THIS chunk's slice has landed. Never 0.
      asm volatile("s_waitcnt vmcnt(4)" ::: "memory");
    }

    const uint4* Wl = &Wall[useWb ? (c & 1) : 0][wave][0];
#pragma unroll
    for (int t = 0; t < 4; ++t) {
      BF8 bw;
      bw.u = Wl[q * 64 + t * 16 + fx];  // one read, FOUR MFMAs
#pragma unroll
      for (int a = 0; a < 4; ++a)
        acc[a][t] = __builtin_amdgcn_mfma_f32_16x16x32_bf16(af[a], bw.v, acc[a][t], 0, 0, 0);
    }
    // no barrier: Wall[*][wave] is wave-private, positions are read-only.
  }

  // ---- 8-way K-merge tree via LDS (reuse Wall: 4096 f32x4 = 4 x 1024) ----
  f32x4* mbv = (f32x4*)Wall;
  // explicit drain: the wrap-around dummy DMA (lands in Wall[0]) must complete
  // before Wall is reused as merge scratch. Each wave drains its own queue.
  if (useWb) asm volatile("s_waitcnt vmcnt(0)" ::: "memory");
  __syncthreads();  // all waves' DMAs drained; all waves done computing
  if (wave >= 4) {
#pragma unroll
    for (int a = 0; a < 4; ++a)
#pragma unroll
      for (int t = 0; t < 4; ++t)
        mbv[(wave - 4) * 1024 + (a * 4 + t) * 64 + lane] = acc[a][t];
  }
  __syncthreads();
  if (wave < 4) {
#pragma unroll
    for (int a = 0; a < 4; ++a)
#pragma unroll
      for (int t = 0; t < 4; ++t)
        acc[a][t] += mbv[wave * 1024 + (a * 4 + t) * 64 + lane];
  }
  __syncthreads();
  if (wave == 2 || wave == 3) {
#pragma unroll
    for (int a = 0; a < 4; ++a)
#pragma unroll
      for (int t = 0; t < 4; ++t)
        mbv[(wave - 2) * 1024 + (a * 4 + t) * 64 + lane] = acc[a][t];
  }
  __syncthreads();
  if (wave < 2) {
#pragma unroll
    for (int a = 0; a < 4; ++a)
#pragma unroll
      for (int t = 0; t < 4; ++t)
        acc[a][t] += mbv[wave * 1024 + (a * 4 + t) * 64 + lane];
  }
  __syncthreads();
  // final swap: wave0 keeps frags 0,1 / wave1 keeps frags 2,3
  if (wave < 2) {
#pragma unroll
    for (int ai = 0; ai < 2; ++ai) {
      const int a = (wave == 0) ? (2 + ai) : ai;
#pragma unroll
      for (int t = 0; t < 4; ++t)
        mbv[(2 + wave) * 1024 + (ai * 4 + t) * 64 + lane] = acc[a][t];
    }
  }
  __syncthreads();
  if (wave < 2) {
    const int src = (wave == 0) ? 3 : 2;
#pragma unroll
    for (int ai = 0; ai < 2; ++ai) {
      const int a = wave * 2 + ai;
#pragma unroll
      for (int t = 0; t < 4; ++t)
        acc[a][t] += mbv[src * 1024 + (ai * 4 + t) * 64 + lane];
    }

    // epilogue: bias + LayerNorm(64) + SiLU. C/D layout: col=lane&15, row=q*4+r.
    float bb[4], gg[4], be[4];
#pragma unroll
    for (int t = 0; t < 4; ++t) {
      bb[t] = bias[t * 16 + fx];
      gg[t] = gamma[t * 16 + fx];
      be[t] = beta[t * 16 + fx];
    }
    float* outB = out + ((size_t)batch * N_PTS + nb) * FEATD;
#pragma unroll
    for (int ai = 0; ai < 2; ++ai) {
      const int a = wave * 2 + ai;
#pragma unroll
      for (int r = 0; r < 4; ++r) {
        float x[4], d[4];
#pragma unroll
        for (int t = 0; t < 4; ++t) x[t] = acc[a][t][r] + bb[t];
        float s = x[0] + x[1] + x[2] + x[3];
        s += __shfl_xor(s, 1); s += __shfl_xor(s, 2);
        s += __shfl_xor(s, 4); s += __shfl_xor(s, 8);
        float mu = s * (1.f / 64.f);
        float v = 0.f;
#pragma unroll
        for (int t = 0; t < 4; ++t) { d[t] = x[t] - mu; v += d[t] * d[t]; }
        v += __shfl_xor(v, 1); v += __shfl_xor(v, 2);
        v += __shfl_xor(v, 4); v += __shfl_xor(v, 8);
        float rstd = __builtin_amdgcn_rsqf(v * (1.f / 64.f) + 1e-5f);
        float* orow = outB + (a * 16 + q * 4 + r) * FEATD;
#pragma unroll
        for (int t = 0; t < 4; ++t) {
          float xn = d[t] * rstd * gg[t] + be[t];
          float y = xn * (1.f / (1.f + __expf(-xn)));  // SiLU
          orow[t * 16 + fx] = y;
        }
      }
    }
  }
}

extern "C" void kernel_launch(void* const* d_in, const int* in_sizes, int n_in,
                              void* d_out, int out_size, void* d_ws, size_t ws_size,
                              hipStream_t stream) {
  const float* pos   = (const float*)d_in[0];  // (4,4096,3)
  const float* W     = (const float*)d_in[1];  // (64,4096)
  const float* bias  = (const float*)d_in[2];  // (64,)
  const float* gamma = (const float*)d_in[3];  // (64,)
  const float* beta  = (const float*)d_in[4];  // (64,)
  float* out = (float*)d_out;                  // (4,4096,64)

  const size_t wb_bytes = (size_t)FEATD * N_PTS * sizeof(unsigned short);  // 512 KiB
  int use_ws = (d_ws != nullptr && ws_size >= wb_bytes);
  unsigned short* Wbt = use_ws ? (unsigned short*)d_ws : nullptr;

  if (use_ws) {
    wconv_kernel<<<dim3((FEATD * N_PTS / 8) / 256), dim3(256), 0, stream>>>(W, Wbt);
  }
  frp_kernel<<<dim3(256), dim3(512), 0, stream>>>(pos, W, bias, gamma, beta, Wbt, out);
}

// Round 3
// 91.274 us; speedup vs baseline: 1.2421x; 1.2421x over previous
//
#include <hip/hip_runtime.h>

// FeatureWithRelativePosition: fused pairwise-dist -> Linear(4096->64) -> LN -> SiLU
// BS=4, N=4096, FEAT=64. fp32 in/out, bf16 MFMA inner product, fp32 accumulate.
//
// R6: zero-barrier K-loop with NO LDS in the loop. 16 waves/block (1024 thr,
//     4 waves/SIMD -- R5's 2/SIMD was the regression: all pipes <25% busy).
//     wave = (rowset rs in {0,1} x 32 rows, k-slice ksl in 0..7 x 512 k).
//     Per kstep (32 k): 6 pos dwordx4 direct from global (L1/L2-hit, 16-lane
//     uniform) + 4 W dwordx4 direct from granule-major bf16 Wbt into regs
//     (issued before the ~300-cyc distance VALU block -> latency self-hides).
//     acc[2][4] = 32 VGPR keeps total ~105 < 128-VGPR cliff for 4 waves/SIMD.
//     LDS = 64 KiB merge scratch only; 5 barriers total, all in the epilogue.

typedef float f32x4 __attribute__((ext_vector_type(4)));
typedef __bf16 bf16x8 __attribute__((ext_vector_type(8)));

union BF8 { bf16x8 v; uint4 u; };

#define N_PTS 4096
#define FEATD 64

// ---- pre-pass: W fp32 [64][4096] -> bf16 granule-major Wbt[512][64][8] ----
// uint4 slot (G*64 + f) holds W[f][G*8 .. G*8+7] as bf16.
__global__ void wconv_kernel(const float* __restrict__ W,
                             unsigned short* __restrict__ Wbt) {
  int gid = blockIdx.x * blockDim.x + threadIdx.x;  // 32768 = 64 f * 512 G
  int f = gid >> 9, m8 = gid & 511;
  const float4* src = (const float4*)(W + (size_t)f * N_PTS + m8 * 8);
  float4 a = src[0], b = src[1];
  BF8 o;
  o.v[0] = (__bf16)a.x; o.v[1] = (__bf16)a.y; o.v[2] = (__bf16)a.z; o.v[3] = (__bf16)a.w;
  o.v[4] = (__bf16)b.x; o.v[5] = (__bf16)b.y; o.v[6] = (__bf16)b.z; o.v[7] = (__bf16)b.w;
  ((uint4*)Wbt)[(size_t)m8 * 64 + f] = o.u;
}

// grid = 256 blocks (batch = bid>>6, rowtile = (bid&63)*64), block = 1024 thr.
// wave: rs = wave&1 (rows rs*32..rs*32+31), ksl = wave>>1 (k = ksl*512..+511).
__global__ __launch_bounds__(1024, 4) void frp_kernel(
    const float* __restrict__ pos, const float* __restrict__ W,
    const float* __restrict__ bias, const float* __restrict__ gamma,
    const float* __restrict__ beta, const unsigned short* __restrict__ Wbt,
    float* __restrict__ out) {
  __shared__ f32x4 mbv[4096];  // 64 KiB merge scratch (loop itself uses no LDS)

  const int tid = threadIdx.x;
  const int lane = tid & 63;
  const int wave = tid >> 6;       // 0..15
  const int rs  = wave & 1;        // rowset: 32 rows
  const int ksl = wave >> 1;       // 0..7: contiguous 512-k slice
  const int fx = lane & 15;
  const int q = lane >> 4;         // granule select within kstep

  const int batch = blockIdx.x >> 6;
  const int nb = (blockIdx.x & 63) * 64;
  const float* posB = pos + (size_t)batch * N_PTS * 3;
  const float4* p4 = (const float4*)posB;

  // this lane's two A-rows (A-frag row = lane&15), direct global reads
  float pxr[2], pyr[2], pzr[2];
#pragma unroll
  for (int a = 0; a < 2; ++a) {
    int r = nb + rs * 32 + a * 16 + fx;
    pxr[a] = posB[r * 3 + 0];
    pyr[a] = posB[r * 3 + 1];
    pzr[a] = posB[r * 3 + 2];
  }

  f32x4 acc[2][4];
#pragma unroll
  for (int a = 0; a < 2; ++a)
#pragma unroll
    for (int t = 0; t < 4; ++t) acc[a][t] = (f32x4){0.f, 0.f, 0.f, 0.f};

  const uint4* Wg = (const uint4*)Wbt;
  const bool useWb = (Wbt != nullptr);

#pragma unroll 2
  for (int s = 0; s < 16; ++s) {
    const int G = ksl * 64 + s * 4 + q;  // this lane's granule (8 points)

    // ---- loads first: 6 pos vec4 (96 B, uniform per 16-lane group) + 4 W ----
    float4 f0 = p4[G * 6 + 0], f1 = p4[G * 6 + 1], f2 = p4[G * 6 + 2];
    float4 f3 = p4[G * 6 + 3], f4 = p4[G * 6 + 4], f5 = p4[G * 6 + 5];

    uint4 bw[4];
    if (useWb) {
#pragma unroll
      for (int t = 0; t < 4; ++t) bw[t] = Wg[G * 64 + t * 16 + fx];
    } else {
#pragma unroll
      for (int t = 0; t < 4; ++t) {
        const float4* src = (const float4*)(W + (size_t)(t * 16 + fx) * N_PTS + G * 8);
        float4 a4 = src[0], b4 = src[1];
        BF8 o;
        o.v[0] = (__bf16)a4.x; o.v[1] = (__bf16)a4.y; o.v[2] = (__bf16)a4.z; o.v[3] = (__bf16)a4.w;
        o.v[4] = (__bf16)b4.x; o.v[5] = (__bf16)b4.y; o.v[6] = (__bf16)b4.z; o.v[7] = (__bf16)b4.w;
        bw[t] = o.u;
      }
    }

    // AoS -> SoA is free at register level (componentwise consumers)
    f32x4 xa = (f32x4){f0.x, f0.w, f1.z, f2.y};
    f32x4 xb = (f32x4){f3.x, f3.w, f4.z, f5.y};
    f32x4 ya = (f32x4){f0.y, f1.x, f1.w, f2.z};
    f32x4 yb = (f32x4){f3.y, f4.x, f4.w, f5.z};
    f32x4 za = (f32x4){f0.z, f1.y, f2.x, f2.w};
    f32x4 zb = (f32x4){f3.z, f4.y, f5.x, f5.w};

    bf16x8 af[2];
#pragma unroll
    for (int a = 0; a < 2; ++a) {
      f32x4 dx = xa - pxr[a], dy = ya - pyr[a], dz = za - pzr[a];
      f32x4 sq = dx * dx + dy * dy + dz * dz;
#pragma unroll
      for (int j = 0; j < 4; ++j) af[a][j] = (__bf16)__builtin_amdgcn_sqrtf(sq[j]);
      dx = xb - pxr[a]; dy = yb - pyr[a]; dz = zb - pzr[a];
      sq = dx * dx + dy * dy + dz * dz;
#pragma unroll
      for (int j = 0; j < 4; ++j) af[a][4 + j] = (__bf16)__builtin_amdgcn_sqrtf(sq[j]);
    }

    // W loads have had the whole VALU block to land (compiler-placed vmcnt)
#pragma unroll
    for (int t = 0; t < 4; ++t) {
      BF8 bwv;
      bwv.u = bw[t];
#pragma unroll
      for (int a = 0; a < 2; ++a)
        acc[a][t] = __builtin_amdgcn_mfma_f32_16x16x32_bf16(af[a], bwv.v, acc[a][t], 0, 0, 0);
    }
  }

  // ---- 8-way K-merge tree per rowset. region w: mbv[w*512 + (a*4+t)*64 + lane]
  // Round 1: ksl>=4 write region (ksl-4)*2+rs; ksl<4 add from region ksl*2+rs.
  if (ksl >= 4) {
    int w = (ksl - 4) * 2 + rs;
#pragma unroll
    for (int a = 0; a < 2; ++a)
#pragma unroll
      for (int t = 0; t < 4; ++t)
        mbv[w * 512 + (a * 4 + t) * 64 + lane] = acc[a][t];
  }
  __syncthreads();
  if (ksl < 4) {
    int w = ksl * 2 + rs;
#pragma unroll
    for (int a = 0; a < 2; ++a)
#pragma unroll
      for (int t = 0; t < 4; ++t)
        acc[a][t] += mbv[w * 512 + (a * 4 + t) * 64 + lane];
  }
  __syncthreads();
  // Round 2: ksl in {2,3} write region (ksl-2)*2+rs; ksl in {0,1} add.
  if (ksl == 2 || ksl == 3) {
    int w = (ksl - 2) * 2 + rs;
#pragma unroll
    for (int a = 0; a < 2; ++a)
#pragma unroll
      for (int t = 0; t < 4; ++t)
        mbv[w * 512 + (a * 4 + t) * 64 + lane] = acc[a][t];
  }
  __syncthreads();
  if (ksl < 2) {
    int w = ksl * 2 + rs;
#pragma unroll
    for (int a = 0; a < 2; ++a)
#pragma unroll
      for (int t = 0; t < 4; ++t)
        acc[a][t] += mbv[w * 512 + (a * 4 + t) * 64 + lane];
  }
  __syncthreads();
  // Round 3: ksl==1 writes region rs; ksl==0 adds.
  if (ksl == 1) {
#pragma unroll
    for (int a = 0; a < 2; ++a)
#pragma unroll
      for (int t = 0; t < 4; ++t)
        mbv[rs * 512 + (a * 4 + t) * 64 + lane] = acc[a][t];
  }
  __syncthreads();
  if (ksl == 0) {
#pragma unroll
    for (int a = 0; a < 2; ++a)
#pragma unroll
      for (int t = 0; t < 4; ++t)
        acc[a][t] += mbv[rs * 512 + (a * 4 + t) * 64 + lane];

    // epilogue: bias + LayerNorm(64) + SiLU. C/D layout: col=lane&15, row=q*4+r.
    float bb[4], gg[4], be[4];
#pragma unroll
    for (int t = 0; t < 4; ++t) {
      bb[t] = bias[t * 16 + fx];
      gg[t] = gamma[t * 16 + fx];
      be[t] = beta[t * 16 + fx];
    }
    float* outB = out + ((size_t)batch * N_PTS + nb + rs * 32) * FEATD;
#pragma unroll
    for (int a = 0; a < 2; ++a) {
#pragma unroll
      for (int r = 0; r < 4; ++r) {
        float x[4], d[4];
#pragma unroll
        for (int t = 0; t < 4; ++t) x[t] = acc[a][t][r] + bb[t];
        float s = x[0] + x[1] + x[2] + x[3];
        s += __shfl_xor(s, 1); s += __shfl_xor(s, 2);
        s += __shfl_xor(s, 4); s += __shfl_xor(s, 8);
        float mu = s * (1.f / 64.f);
        float v = 0.f;
#pragma unroll
        for (int t = 0; t < 4; ++t) { d[t] = x[t] - mu; v += d[t] * d[t]; }
        v += __shfl_xor(v, 1); v += __shfl_xor(v, 2);
        v += __shfl_xor(v, 4); v += __shfl_xor(v, 8);
        float rstd = __builtin_amdgcn_rsqf(v * (1.f / 64.f) + 1e-5f);
        float* orow = outB + (a * 16 + q * 4 + r) * FEATD;
#pragma unroll
        for (int t = 0; t < 4; ++t) {
          float xn = d[t] * rstd * gg[t] + be[t];
          float y = xn * (1.f / (1.f + __expf(-xn)));  // SiLU
          orow[t * 16 + fx] = y;
        }
      }
    }
  }
}

extern "C" void kernel_launch(void* const* d_in, const int* in_sizes, int n_in,
                              void* d_out, int out_size, void* d_ws, size_t ws_size,
                              hipStream_t stream) {
  const float* pos   = (const float*)d_in[0];  // (4,4096,3)
  const float* W     = (const float*)d_in[1];  // (64,4096)
  const float* bias  = (const float*)d_in[2];  // (64,)
  const float* gamma = (const float*)d_in[3];  // (64,)
  const float* beta  = (const float*)d_in[4];  // (64,)
  float* out = (float*)d_out;                  // (4,4096,64)

  const size_t wb_bytes = (size_t)FEATD * N_PTS * sizeof(unsigned short);  // 512 KiB
  int use_ws = (d_ws != nullptr && ws_size >= wb_bytes);
  unsigned short* Wbt = use_ws ? (unsigned short*)d_ws : nullptr;

  if (use_ws) {
    wconv_kernel<<<dim3((FEATD * N_PTS / 8) / 256), dim3(256), 0, stream>>>(W, Wbt);
  }
  frp_kernel<<<dim3(256), dim3(1024), 0, stream>>>(pos, W, bias, gamma, beta, Wbt, out);
}

// Round 4
// 88.977 us; speedup vs baseline: 1.2742x; 1.0258x over previous
//
#include <hip/hip_runtime.h>

// FeatureWithRelativePosition: fused pairwise-dist -> Linear(4096->64) -> LN -> SiLU
// BS=4, N=4096, FEAT=64. fp32 in/out, bf16 MFMA inner product, fp32 accumulate.
//
// R7: R4 structure (best measured: frp ~29 us) + T3/T4 barrier fix.
//     - W triple-buffered (3 x 32 KiB), DMA prefetch TWO chunks ahead.
//     - in-loop sync = counted "s_waitcnt vmcnt(2)" + RAW s_barrier +
//       sched_barrier(0)  -- the just-issued chunk-(c+2) DMAs stay in flight
//       across the barrier instead of being drained by the compiler's
//       vmcnt(0)-before-__syncthreads (R4's structural stall, ~16 us of its
//       29). vmcnt counting is exact: no other VMEM ops in the useWb loop.
//     - everything else (wave partition 2 rowsets x 8 K-slices, frag math,
//       K-merge tree, epilogue) is verbatim R4.

typedef float f32x4 __attribute__((ext_vector_type(4)));
typedef __bf16 bf16x8 __attribute__((ext_vector_type(8)));

union BF8 { bf16x8 v; uint4 u; };

#define N_PTS 4096
#define FEATD 64
#define BK 256
#define NCH (N_PTS / BK)

// ---- pre-pass: W fp32 [64][4096] -> bf16 granule-major Wbt[512][64][8] ----
// uint4 slot (G*64 + f) holds W[f][G*8 .. G*8+7] as bf16.
__global__ void wconv_kernel(const float* __restrict__ W,
                             unsigned short* __restrict__ Wbt) {
  int gid = blockIdx.x * blockDim.x + threadIdx.x;  // 32768 = 64 f * 512 G
  int f = gid >> 9, m8 = gid & 511;
  const float4* src = (const float4*)(W + (size_t)f * N_PTS + m8 * 8);
  float4 a = src[0], b = src[1];
  BF8 o;
  o.v[0] = (__bf16)a.x; o.v[1] = (__bf16)a.y; o.v[2] = (__bf16)a.z; o.v[3] = (__bf16)a.w;
  o.v[4] = (__bf16)b.x; o.v[5] = (__bf16)b.y; o.v[6] = (__bf16)b.z; o.v[7] = (__bf16)b.w;
  ((uint4*)Wbt)[(size_t)m8 * 64 + f] = o.u;
}

__device__ __forceinline__ void load_lds16(const void* g, void* l) {
  __builtin_amdgcn_global_load_lds(
      (const __attribute__((address_space(1))) void*)g,
      (__attribute__((address_space(3))) void*)l, 16, 0, 0);
}

// grid = 256 blocks (batch = bid>>6, rowtile = (bid&63)*64), block = 1024 thr.
// wave&1 = rowset (32 rows), wave>>1 = K-slice (32 k per chunk).
__global__ __launch_bounds__(1024, 4) void frp_kernel(
    const float* __restrict__ pos, const float* __restrict__ W,
    const float* __restrict__ bias, const float* __restrict__ gamma,
    const float* __restrict__ beta, const unsigned short* __restrict__ Wbt,
    float* __restrict__ out) {
  __shared__ uint4 Wbuf[3][2048];            // 96 KiB: slot = g*64 + f
  __shared__ __align__(16) float Px[N_PTS];  // 16 KiB each, SoA
  __shared__ __align__(16) float Py[N_PTS];
  __shared__ __align__(16) float Pz[N_PTS];

  const int tid = threadIdx.x;
  const int lane = tid & 63;
  const int wave = tid >> 6;
  const int rs  = wave & 1;        // rowset: rows rs*32 .. rs*32+31
  const int ksl = wave >> 1;       // 0..7: k-slice (granules ksl*4..ksl*4+3)
  const int fx = lane & 15;
  const int q = lane >> 4;

  const int batch = blockIdx.x >> 6;
  const int nb = (blockIdx.x & 63) * 64;
  const float* posB = pos + (size_t)batch * N_PTS * 3;

  // ---- stage ALL positions SoA (once). 1024 thr x 4 pts, float4 in/out. ----
  {
    const float4* p4 = (const float4*)posB;
    float4 f0 = p4[tid * 3 + 0];
    float4 f1 = p4[tid * 3 + 1];
    float4 f2 = p4[tid * 3 + 2];
    ((float4*)Px)[tid] = make_float4(f0.x, f0.w, f1.z, f2.y);
    ((float4*)Py)[tid] = make_float4(f0.y, f1.x, f1.w, f2.z);
    ((float4*)Pz)[tid] = make_float4(f0.z, f1.y, f2.x, f2.w);
  }

  const bool useWb = (Wbt != nullptr);

  // ---- W chunk staging: 2048 consecutive uint4s (granule-major) ----
  auto stageW = [&](int c, int b) {
#pragma unroll
    for (int it = 0; it < 2; ++it) {
      int gi = it * 1024 + tid;
      if (useWb) {
        load_lds16(Wbt + ((size_t)c * 2048 + gi) * 8, &Wbuf[b][gi]);
      } else {
        int g = gi >> 6, f = gi & 63;
        const float4* src = (const float4*)(W + (size_t)f * N_PTS + c * BK + g * 8);
        float4 a = src[0], b2 = src[1];
        BF8 o;
        o.v[0] = (__bf16)a.x;  o.v[1] = (__bf16)a.y;  o.v[2] = (__bf16)a.z;  o.v[3] = (__bf16)a.w;
        o.v[4] = (__bf16)b2.x; o.v[5] = (__bf16)b2.y; o.v[6] = (__bf16)b2.z; o.v[7] = (__bf16)b2.w;
        Wbuf[b][gi] = o.u;
      }
    }
  };

  f32x4 acc[2][4];
#pragma unroll
  for (int a = 0; a < 2; ++a)
#pragma unroll
    for (int t = 0; t < 4; ++t) acc[a][t] = (f32x4){0.f, 0.f, 0.f, 0.f};

  stageW(0, 0);
  stageW(1, 1);
  __syncthreads();   // one-time full drain: pos staging + chunks 0,1 landed

  // this lane's two A-rows (A-frag row = lane&15); read from LDS (broadcast)
  const int nrow0 = nb + rs * 32 + fx;
  const float px0 = Px[nrow0],      py0 = Py[nrow0],      pz0 = Pz[nrow0];
  const float px1 = Px[nrow0 + 16], py1 = Py[nrow0 + 16], pz1 = Pz[nrow0 + 16];

  const int g8 = ksl * 4 + q;          // this lane's granule (8 pts) within chunk

  for (int c = 0; c < NCH; ++c) {
    if (c + 2 < NCH) stageW(c + 2, (c + 2) % 3);  // DMA 2 chunks ahead
    const uint4* Wcur = Wbuf[c % 3];
    const int m4 = c * 64 + g8 * 2;               // f32x4 index into SoA arrays
    f32x4 xa = ((const f32x4*)Px)[m4], xb = ((const f32x4*)Px)[m4 + 1];
    f32x4 ya = ((const f32x4*)Py)[m4], yb = ((const f32x4*)Py)[m4 + 1];
    f32x4 za = ((const f32x4*)Pz)[m4], zb = ((const f32x4*)Pz)[m4 + 1];

    bf16x8 af0, af1;
    {
      f32x4 dx = xa - px0, dy = ya - py0, dz = za - pz0;
      f32x4 sq = dx * dx + dy * dy + dz * dz;
#pragma unroll
      for (int j = 0; j < 4; ++j) af0[j] = (__bf16)__builtin_amdgcn_sqrtf(sq[j]);
      dx = xb - px0; dy = yb - py0; dz = zb - pz0;
      sq = dx * dx + dy * dy + dz * dz;
#pragma unroll
      for (int j = 0; j < 4; ++j) af0[4 + j] = (__bf16)__builtin_amdgcn_sqrtf(sq[j]);
      dx = xa - px1; dy = ya - py1; dz = za - pz1;
      sq = dx * dx + dy * dy + dz * dz;
#pragma unroll
      for (int j = 0; j < 4; ++j) af1[j] = (__bf16)__builtin_amdgcn_sqrtf(sq[j]);
      dx = xb - px1; dy = yb - py1; dz = zb - pz1;
      sq = dx * dx + dy * dy + dz * dz;
#pragma unroll
      for (int j = 0; j < 4; ++j) af1[4 + j] = (__bf16)__builtin_amdgcn_sqrtf(sq[j]);
    }
#pragma unroll
    for (int t = 0; t < 4; ++t) {
      BF8 bw;
      bw.u = Wcur[g8 * 64 + t * 16 + fx];   // one read, two MFMAs
      acc[0][t] = __builtin_amdgcn_mfma_f32_16x16x32_bf16(af0, bw.v, acc[0][t], 0, 0, 0);
      acc[1][t] = __builtin_amdgcn_mfma_f32_16x16x32_bf16(af1, bw.v, acc[1][t], 0, 0, 0);
    }

    if (useWb) {
      // T4: counted wait. Outstanding per thread = 2 loads of chunk c+2 (just
      // issued) + 2 of chunk c+1 (issued last iter). vmcnt(2) = c+1 landed,
      // c+2 stays in flight across the barrier. Tail: drain fully.
      if (c < NCH - 2) asm volatile("s_waitcnt vmcnt(2)" ::: "memory");
      else             asm volatile("s_waitcnt vmcnt(0)" ::: "memory");
      __builtin_amdgcn_s_barrier();          // raw: no compiler vmcnt(0) drain
      __builtin_amdgcn_sched_barrier(0);     // pin next iter's ds_reads below
    } else {
      __syncthreads();
    }
  }

  // ---- 8-way K-merge via LDS (reuse Wbuf; merge needs 64 KiB of the 96) ----
  f32x4* mbv = (f32x4*)Wbuf;
  // region w (0..7): mbv[w*512 + (a*4+t)*64 + lane]
  __syncthreads();  // all waves done computing; all DMAs drained (tail vmcnt(0))
  if (ksl >= 4) {
    int w = (ksl - 4) * 2 + rs;
#pragma unroll
    for (int a = 0; a < 2; ++a)
#pragma unroll
      for (int t = 0; t < 4; ++t)
        mbv[w * 512 + (a * 4 + t) * 64 + lane] = acc[a][t];
  }
  __syncthreads();
  if (ksl < 4) {
    int w = ksl * 2 + rs;
#pragma unroll
    for (int a = 0; a < 2; ++a)
#pragma unroll
      for (int t = 0; t < 4; ++t)
        acc[a][t] += mbv[w * 512 + (a * 4 + t) * 64 + lane];
  }
  __syncthreads();
  if (ksl >= 1 && ksl < 4) {
    int w = (ksl - 1) * 2 + rs;
#pragma unroll
    for (int a = 0; a < 2; ++a)
#pragma unroll
      for (int t = 0; t < 4; ++t)
        mbv[w * 512 + (a * 4 + t) * 64 + lane] = acc[a][t];
  }
  __syncthreads();
  if (ksl == 0) {
#pragma unroll
    for (int s = 0; s < 3; ++s)
#pragma unroll
      for (int a = 0; a < 2; ++a)
#pragma unroll
        for (int t = 0; t < 4; ++t)
          acc[a][t] += mbv[(s * 2 + rs) * 512 + (a * 4 + t) * 64 + lane];

    // epilogue: bias + LayerNorm(64) + SiLU. C/D layout: col=lane&15, row=q*4+r.
    float bb[4], gg[4], be[4];
#pragma unroll
    for (int t = 0; t < 4; ++t) {
      bb[t] = bias[t * 16 + fx];
      gg[t] = gamma[t * 16 + fx];
      be[t] = beta[t * 16 + fx];
    }
    float* outB = out + ((size_t)batch * N_PTS + nb + rs * 32) * FEATD;
#pragma unroll
    for (int a = 0; a < 2; ++a) {
#pragma unroll
      for (int r = 0; r < 4; ++r) {
        float x[4], d[4];
#pragma unroll
        for (int t = 0; t < 4; ++t) x[t] = acc[a][t][r] + bb[t];
        float s = x[0] + x[1] + x[2] + x[3];
        s += __shfl_xor(s, 1); s += __shfl_xor(s, 2);
        s += __shfl_xor(s, 4); s += __shfl_xor(s, 8);
        float mu = s * (1.f / 64.f);
        float v = 0.f;
#pragma unroll
        for (int t = 0; t < 4; ++t) { d[t] = x[t] - mu; v += d[t] * d[t]; }
        v += __shfl_xor(v, 1); v += __shfl_xor(v, 2);
        v += __shfl_xor(v, 4); v += __shfl_xor(v, 8);
        float rstd = __builtin_amdgcn_rsqf(v * (1.f / 64.f) + 1e-5f);
        float* orow = outB + (a * 16 + q * 4 + r) * FEATD;
#pragma unroll
        for (int t = 0; t < 4; ++t) {
          float xn = d[t] * rstd * gg[t] + be[t];
          float y = xn * (1.f / (1.f + __expf(-xn)));  // SiLU
          orow[t * 16 + fx] = y;
        }
      }
    }
  }
}

extern "C" void kernel_launch(void* const* d_in, const int* in_sizes, int n_in,
                              void* d_out, int out_size, void* d_ws, size_t ws_size,
                              hipStream_t stream) {
  const float* pos   = (const float*)d_in[0];  // (4,4096,3)
  const float* W     = (const float*)d_in[1];  // (64,4096)
  const float* bias  = (const float*)d_in[2];  // (64,)
  const float* gamma = (const float*)d_in[3];  // (64,)
  const float* beta  = (const float*)d_in[4];  // (64,)
  float* out = (float*)d_out;                  // (4,4096,64)

  const size_t wb_bytes = (size_t)FEATD * N_PTS * sizeof(unsigned short);  // 512 KiB
  int use_ws = (d_ws != nullptr && ws_size >= wb_bytes);
  unsigned short* Wbt = use_ws ? (unsigned short*)d_ws : nullptr;

  if (use_ws) {
    wconv_kernel<<<dim3((FEATD * N_PTS / 8) / 256), dim3(256), 0, stream>>>(W, Wbt);
  }
  frp_kernel<<<dim3(256), dim3(1024), 0, stream>>>(pos, W, bias, gamma, beta, Wbt, out);
}